// Round 1
// baseline (508.225 us; speedup 1.0000x reference)
//
#include <hip/hip_runtime.h>
#include <hip/hip_bf16.h>

typedef unsigned short ushort_t;
typedef __attribute__((ext_vector_type(8))) short short8;   // 8 bf16 = 4 VGPRs (MFMA A/B frag)
typedef __attribute__((ext_vector_type(4))) float f32x4;    // MFMA C/D frag
typedef __attribute__((ext_vector_type(4))) float f4;

#define NB 4
#define SS 1024
#define HH 2048
#define NH 16
#define DD 128
#define MM (NB*SS)          // 4096 rows for projections

__device__ __forceinline__ ushort_t f2bf(float x) {
    __hip_bfloat16 h = __float2bfloat16(x);
    return *(ushort_t*)&h;
}
__device__ __forceinline__ float bf2f(ushort_t u) {
    __hip_bfloat16 h; *(ushort_t*)&h = u;
    return __bfloat162float(h);
}

__device__ __forceinline__ f32x4 mfma16(short8 a, short8 b, f32x4 c) {
    return __builtin_amdgcn_mfma_f32_16x16x32_bf16(a, b, c, 0, 0, 0);
}

__device__ __forceinline__ void load_lds16(const ushort_t* g, ushort_t* l) {
    __builtin_amdgcn_global_load_lds(
        (const __attribute__((address_space(1))) unsigned int*)g,
        (__attribute__((address_space(3))) unsigned int*)l,
        16, 0, 0);
}

// ---------------- prep: split f32 -> bf16 hi/lo ----------------
__global__ void k_split(const float* __restrict__ src, ushort_t* __restrict__ hi,
                        ushort_t* __restrict__ lo, int n) {
    int i = (blockIdx.x * blockDim.x + threadIdx.x) * 4;
    if (i + 3 < n) {
        f4 v = *(const f4*)(src + i);
        for (int j = 0; j < 4; ++j) {
            float x = v[j];
            ushort_t h = f2bf(x);
            hi[i + j] = h;
            lo[i + j] = f2bf(x - bf2f(h));
        }
    }
}

// transpose weight [Nn][Hd][Dd] -> [Nn][Dd][Hd] and split
__global__ void k_prep_w(const float* __restrict__ W, ushort_t* __restrict__ Thi,
                         ushort_t* __restrict__ Tlo, int Nn, int Hd, int Dd) {
    int j = blockIdx.x * blockDim.x + threadIdx.x;
    int total = Nn * Hd * Dd;
    if (j >= total) return;
    int n = j / (Dd * Hd);
    int r = j % (Dd * Hd);
    int d = r / Hd;
    int h = r % Hd;
    float x = W[((size_t)n * Hd + h) * Dd + d];
    ushort_t hb = f2bf(x);
    Thi[j] = hb;
    if (Tlo) Tlo[j] = f2bf(x - bf2f(hb));
}

// ---------------- split-bf16 GEMM ----------------
// A [M][K] (row-major, K-major), Bt [128][K] (weight transposed), C = A*Bt^T + bias
// TERMS==3: hi*hi + hi*lo + lo*hi (Q,K).  TERMS==1: hi*hi only (V).
template<int TERMS, bool SPLIT_OUT>
__global__ __launch_bounds__(256) void k_gemm(
    const ushort_t* __restrict__ Ah, const ushort_t* __restrict__ Al,
    const ushort_t* __restrict__ Bh, const ushort_t* __restrict__ Bl,
    const float* __restrict__ bias,
    ushort_t* __restrict__ Oh, ushort_t* __restrict__ Ol) {

    constexpr int BK = 32;
    __shared__ ushort_t sAh[128 * BK], sBh[128 * BK];
    __shared__ ushort_t sAl[(TERMS == 3) ? 128 * BK : 8];
    __shared__ ushort_t sBl[(TERMS == 3) ? 128 * BK : 8];

    const int tid = threadIdx.x;
    const int w = tid >> 6, l = tid & 63;
    const int m0 = blockIdx.x * 128;
    const int z = blockIdx.z;

    Bh += (size_t)z * DD * HH;
    if (TERMS == 3) Bl += (size_t)z * DD * HH;
    bias += (size_t)z * DD;
    Oh += (size_t)z * MM * DD;
    if (SPLIT_OUT) Ol += (size_t)z * MM * DD;

    const int wr = w >> 1, wc = w & 1;
    f32x4 acc[4][4] = {};

    for (int kt = 0; kt < HH / BK; ++kt) {
        const int k0 = kt * BK;
        // stage 128x32 tiles (8KB each) : 8 chunks of 1KB, 2 per wave per matrix
        for (int c = 0; c < 2; ++c) {
            int chunk = c * 4 + w;
            int idx = chunk * 512 + l * 8;      // elem within tile
            int row = idx >> 5, kc = idx & 31;
            load_lds16(Ah + (size_t)(m0 + row) * HH + k0 + kc, &sAh[chunk * 512]);
            load_lds16(Bh + (size_t)row * HH + k0 + kc, &sBh[chunk * 512]);
            if constexpr (TERMS == 3) {
                load_lds16(Al + (size_t)(m0 + row) * HH + k0 + kc, &sAl[chunk * 512]);
                load_lds16(Bl + (size_t)row * HH + k0 + kc, &sBl[chunk * 512]);
            }
        }
        __syncthreads();

        short8 aH[4], bH[4], aL[4], bL[4];
        for (int i = 0; i < 4; ++i) {
            int ra = wr * 64 + i * 16 + (l & 15);
            int rb = wc * 64 + i * 16 + (l & 15);
            aH[i] = *(const short8*)&sAh[ra * 32 + (l >> 4) * 8];
            bH[i] = *(const short8*)&sBh[rb * 32 + (l >> 4) * 8];
            if constexpr (TERMS == 3) {
                aL[i] = *(const short8*)&sAl[ra * 32 + (l >> 4) * 8];
                bL[i] = *(const short8*)&sBl[rb * 32 + (l >> 4) * 8];
            }
        }
        for (int i = 0; i < 4; ++i)
            for (int j = 0; j < 4; ++j) {
                acc[i][j] = mfma16(aH[i], bH[j], acc[i][j]);
                if constexpr (TERMS == 3) {
                    acc[i][j] = mfma16(aH[i], bL[j], acc[i][j]);
                    acc[i][j] = mfma16(aL[i], bH[j], acc[i][j]);
                }
            }
        __syncthreads();
    }

    // epilogue: +bias, split to bf16 hi/lo
    for (int i = 0; i < 4; ++i) {
        int row = m0 + wr * 64 + i * 16 + ((l >> 4) << 2);
        for (int j = 0; j < 4; ++j) {
            int col = wc * 64 + j * 16 + (l & 15);
            float bv = bias[col];
            for (int r = 0; r < 4; ++r) {
                float cv = acc[i][j][r] + bv;
                size_t o = (size_t)(row + r) * DD + col;
                ushort_t h = f2bf(cv);
                Oh[o] = h;
                if constexpr (SPLIT_OUT) Ol[o] = f2bf(cv - bf2f(h));
            }
        }
    }
}

// ---------------- flash attention ----------------
// grid (S/64, N, B), 256 thr = 4 waves, each wave owns 16 q-rows.
// Q [N][B*S][D] split bf16; K [B*S][D] split bf16; V [B*S][D] bf16; Out [B][N][S][D] f32.
__global__ __launch_bounds__(256) void k_attn(
    const ushort_t* __restrict__ Qh, const ushort_t* __restrict__ Ql,
    const ushort_t* __restrict__ Kh, const ushort_t* __restrict__ Kl,
    const ushort_t* __restrict__ Vv, float* __restrict__ Out) {

    __shared__ ushort_t sKh[32 * 128], sKl[32 * 128];
    __shared__ ushort_t sVt[128 * 32];          // V transposed [d][t]
    __shared__ ushort_t sP[4 * 16 * 32];        // per-wave P tile

    const int tid = threadIdx.x;
    const int w = tid >> 6, l = tid & 63;
    const int q0 = blockIdx.x * 64;
    const int n = blockIdx.y, b = blockIdx.z;

    // Q fragments (held in registers whole kernel): rows q0+w*16+(l&15)
    short8 qH[4], qL[4];
    {
        size_t base = ((size_t)n * MM + b * SS + q0 + w * 16 + (l & 15)) * DD + ((l >> 4) * 8);
        for (int kk = 0; kk < 4; ++kk) {
            qH[kk] = *(const short8*)&Qh[base + kk * 32];
            qL[kk] = *(const short8*)&Ql[base + kk * 32];
        }
    }

    f32x4 accO[8] = {};
    float m[4] = {-3.0e38f, -3.0e38f, -3.0e38f, -3.0e38f};
    float lsum[4] = {0.f, 0.f, 0.f, 0.f};

    for (int t0 = 0; t0 < SS; t0 += 32) {
        // stage K hi/lo (32x128) via global_load_lds
        for (int c = 0; c < 2; ++c) {
            int chunk = c * 4 + w;
            int idx = chunk * 512 + l * 8;
            int row = idx >> 7, col = idx & 127;
            size_t g = ((size_t)b * SS + t0 + row) * DD + col;
            load_lds16(Kh + g, &sKh[chunk * 512]);
            load_lds16(Kl + g, &sKl[chunk * 512]);
        }
        // stage V transposed (register path, scalar LDS writes)
        {
            int r = tid >> 3, d0 = (tid & 7) * 16;
            const ushort_t* g = Vv + ((size_t)b * SS + t0 + r) * DD + d0;
            short8 v0 = *(const short8*)g;
            short8 v1 = *(const short8*)(g + 8);
            for (int j = 0; j < 8; ++j) sVt[(d0 + j) * 32 + r] = (ushort_t)v0[j];
            for (int j = 0; j < 8; ++j) sVt[(d0 + 8 + j) * 32 + r] = (ushort_t)v1[j];
        }
        __syncthreads();

        // QK^T, 3-term split for f32-accurate logits
        f32x4 s[2] = {};
        for (int ts = 0; ts < 2; ++ts) {
            for (int kk = 0; kk < 4; ++kk) {
                int ridx = (ts * 16 + (l & 15)) * 128 + kk * 32 + (l >> 4) * 8;
                short8 kH = *(const short8*)&sKh[ridx];
                short8 kL = *(const short8*)&sKl[ridx];
                s[ts] = mfma16(qH[kk], kH, s[ts]);
                s[ts] = mfma16(qH[kk], kL, s[ts]);
                s[ts] = mfma16(qL[kk], kH, s[ts]);
            }
        }

        // online softmax (rows live across 16-lane groups, 4 rows/lane in regs)
        float p0[4], p1[4], scl[4];
        for (int r = 0; r < 4; ++r) {
            float v = fmaxf(s[0][r], s[1][r]);
            for (int off = 8; off >= 1; off >>= 1) v = fmaxf(v, __shfl_xor(v, off, 16));
            float mn = fmaxf(m[r], v);
            scl[r] = __expf(m[r] - mn);
            p0[r] = __expf(s[0][r] - mn);
            p1[r] = __expf(s[1][r] - mn);
            float rs = p0[r] + p1[r];
            for (int off = 8; off >= 1; off >>= 1) rs += __shfl_xor(rs, off, 16);
            lsum[r] = lsum[r] * scl[r] + rs;
            m[r] = mn;
        }
        for (int db = 0; db < 8; ++db)
            for (int r = 0; r < 4; ++r) accO[db][r] *= scl[r];

        // P -> LDS (bf16), per-wave region
        for (int r = 0; r < 4; ++r) {
            int q = (l >> 4) * 4 + r;
            sP[w * 512 + q * 32 + (l & 15)] = f2bf(p0[r]);
            sP[w * 512 + q * 32 + 16 + (l & 15)] = f2bf(p1[r]);
        }
        __syncthreads();

        // PV
        short8 pa = *(const short8*)&sP[w * 512 + (l & 15) * 32 + (l >> 4) * 8];
        for (int db = 0; db < 8; ++db) {
            short8 vb = *(const short8*)&sVt[(db * 16 + (l & 15)) * 32 + (l >> 4) * 8];
            accO[db] = mfma16(pa, vb, accO[db]);
        }
        __syncthreads();
    }

    // epilogue: normalize, write f32 out [B][N][S][D]
    for (int r = 0; r < 4; ++r) {
        float inv = 1.0f / lsum[r];
        int q = q0 + w * 16 + (l >> 4) * 4 + r;
        size_t base = (((size_t)b * NH + n) * SS + q) * DD;
        for (int db = 0; db < 8; ++db) {
            Out[base + db * 16 + (l & 15)] = accO[db][r] * inv;
        }
    }
}

// ---------------- workspace layout (bytes) ----------------
#define OFF_HHI   ((size_t)0)
#define OFF_HLO   (OFF_HHI + (size_t)MM*HH*2)
#define OFF_WQTH  (OFF_HLO + (size_t)MM*HH*2)
#define OFF_WQTL  (OFF_WQTH + (size_t)NH*DD*HH*2)
#define OFF_WKTH  (OFF_WQTL + (size_t)NH*DD*HH*2)
#define OFF_WKTL  (OFF_WKTH + (size_t)DD*HH*2)
#define OFF_WVTH  (OFF_WKTL + (size_t)DD*HH*2)
#define OFF_QHI   (OFF_WVTH + (size_t)DD*HH*2)
#define OFF_QLO   (OFF_QHI + (size_t)NH*MM*DD*2)
#define OFF_KHI   (OFF_QLO + (size_t)NH*MM*DD*2)
#define OFF_KLO   (OFF_KHI + (size_t)MM*DD*2)
#define OFF_VBF   (OFF_KLO + (size_t)MM*DD*2)

extern "C" void kernel_launch(void* const* d_in, const int* in_sizes, int n_in,
                              void* d_out, int out_size, void* d_ws, size_t ws_size,
                              hipStream_t stream) {
    const float* hs = (const float*)d_in[0];
    const float* Wq = (const float*)d_in[1];
    const float* bq = (const float*)d_in[2];
    const float* Wk = (const float*)d_in[3];
    const float* bk = (const float*)d_in[4];
    const float* Wv = (const float*)d_in[5];
    const float* bv = (const float*)d_in[6];
    float* out = (float*)d_out;
    char* ws = (char*)d_ws;

    ushort_t* hhi  = (ushort_t*)(ws + OFF_HHI);
    ushort_t* hlo  = (ushort_t*)(ws + OFF_HLO);
    ushort_t* wqth = (ushort_t*)(ws + OFF_WQTH);
    ushort_t* wqtl = (ushort_t*)(ws + OFF_WQTL);
    ushort_t* wkth = (ushort_t*)(ws + OFF_WKTH);
    ushort_t* wktl = (ushort_t*)(ws + OFF_WKTL);
    ushort_t* wvth = (ushort_t*)(ws + OFF_WVTH);
    ushort_t* qhi  = (ushort_t*)(ws + OFF_QHI);
    ushort_t* qlo  = (ushort_t*)(ws + OFF_QLO);
    ushort_t* khi  = (ushort_t*)(ws + OFF_KHI);
    ushort_t* klo  = (ushort_t*)(ws + OFF_KLO);
    ushort_t* vbf  = (ushort_t*)(ws + OFF_VBF);

    // prep
    k_split<<<(MM*HH)/(256*4), 256, 0, stream>>>(hs, hhi, hlo, MM*HH);
    k_prep_w<<<(NH*HH*DD + 255)/256, 256, 0, stream>>>(Wq, wqth, wqtl, NH, HH, DD);
    k_prep_w<<<(HH*DD + 255)/256, 256, 0, stream>>>(Wk, wkth, wktl, 1, HH, DD);
    k_prep_w<<<(HH*DD + 255)/256, 256, 0, stream>>>(Wv, wvth, nullptr, 1, HH, DD);

    // projections
    dim3 gq(MM/128, 1, NH);
    k_gemm<3, true><<<gq, 256, 0, stream>>>(hhi, hlo, wqth, wqtl, bq, qhi, qlo);
    dim3 gk(MM/128, 1, 1);
    k_gemm<3, true><<<gk, 256, 0, stream>>>(hhi, hlo, wkth, wktl, bk, khi, klo);
    k_gemm<1, false><<<gk, 256, 0, stream>>>(hhi, nullptr, wvth, nullptr, bv, vbf, nullptr);

    // attention
    dim3 ga(SS/64, NH, NB);
    k_attn<<<ga, 256, 0, stream>>>(qhi, qlo, khi, klo, vbf, out);
}

// Round 2
// 357.636 us; speedup vs baseline: 1.4211x; 1.4211x over previous
//
#include <hip/hip_runtime.h>
#include <hip/hip_bf16.h>

typedef unsigned short ushort_t;
typedef __attribute__((ext_vector_type(8))) short short8;   // 8 bf16 (MFMA A/B frag)
typedef __attribute__((ext_vector_type(4))) float f32x4;    // MFMA C/D frag
typedef __attribute__((ext_vector_type(4))) float f4;

#define NB 4
#define SS 1024
#define HH 2048
#define NH 16
#define DD 128
#define MM (NB*SS)          // 4096 rows
#define ND 2048             // NH*DD total Q output cols
#define KVB 64              // attention KV tile

__device__ __forceinline__ ushort_t f2bf(float x) {
    __hip_bfloat16 h = __float2bfloat16(x);
    return *(ushort_t*)&h;
}
__device__ __forceinline__ float bf2f(ushort_t u) {
    __hip_bfloat16 h; *(ushort_t*)&h = u;
    return __bfloat162float(h);
}
__device__ __forceinline__ f32x4 mfma16(short8 a, short8 b, f32x4 c) {
    return __builtin_amdgcn_mfma_f32_16x16x32_bf16(a, b, c, 0, 0, 0);
}
__device__ __forceinline__ void load_lds16(const ushort_t* g, ushort_t* l) {
    __builtin_amdgcn_global_load_lds(
        (const __attribute__((address_space(1))) unsigned int*)g,
        (__attribute__((address_space(3))) unsigned int*)l,
        16, 0, 0);
}

// ---------------- prep: split f32 -> bf16 hi/lo ----------------
__global__ void k_split(const float* __restrict__ src, ushort_t* __restrict__ hi,
                        ushort_t* __restrict__ lo, int n) {
    int i = (blockIdx.x * blockDim.x + threadIdx.x) * 4;
    if (i + 3 < n) {
        f4 v = *(const f4*)(src + i);
        for (int j = 0; j < 4; ++j) {
            float x = v[j];
            ushort_t h = f2bf(x);
            hi[i + j] = h;
            lo[i + j] = f2bf(x - bf2f(h));
        }
    }
}

// transpose weight [Nn][Hd][Dd] -> [Nn*Dd][Hd] and split
__global__ void k_prep_w(const float* __restrict__ W, ushort_t* __restrict__ Thi,
                         ushort_t* __restrict__ Tlo, int Nn, int Hd, int Dd) {
    int j = blockIdx.x * blockDim.x + threadIdx.x;
    int total = Nn * Hd * Dd;
    if (j >= total) return;
    int n = j / (Dd * Hd);
    int r = j % (Dd * Hd);
    int d = r / Hd;
    int h = r % Hd;
    float x = W[((size_t)n * Hd + h) * Dd + d];
    ushort_t hb = f2bf(x);
    Thi[j] = hb;
    if (Tlo) Tlo[j] = f2bf(x - bf2f(hb));
}

// ---------------- split-bf16 GEMM ----------------
// A [M][HH], Bt [Ntot][HH] (weight^T), C[M][Ntot] = A*Bt^T + bias
// grid (M/128, Ntot/128). TERMS==3: hi*hi+hi*lo+lo*hi. TERMS==1: hi*hi.
template<int TERMS, bool SPLIT_OUT>
__global__ __launch_bounds__(256) void k_gemm(
    const ushort_t* __restrict__ Ah, const ushort_t* __restrict__ Al,
    const ushort_t* __restrict__ Bh, const ushort_t* __restrict__ Bl,
    const float* __restrict__ bias,
    ushort_t* __restrict__ Oh, ushort_t* __restrict__ Ol, int Ntot) {

    constexpr int BK = 32;
    __shared__ ushort_t sAh[128 * BK], sBh[128 * BK];
    __shared__ ushort_t sAl[(TERMS == 3) ? 128 * BK : 8];
    __shared__ ushort_t sBl[(TERMS == 3) ? 128 * BK : 8];

    const int tid = threadIdx.x;
    const int w = tid >> 6, l = tid & 63;
    const int m0 = blockIdx.x * 128;
    const int n0 = blockIdx.y * 128;
    const int wr = w >> 1, wc = w & 1;
    f32x4 acc[4][4] = {};

    for (int kt = 0; kt < HH / BK; ++kt) {
        const int k0 = kt * BK;
        for (int c = 0; c < 2; ++c) {
            int chunk = c * 4 + w;
            int idx = chunk * 512 + l * 8;
            int row = idx >> 5, kc = idx & 31;
            load_lds16(Ah + (size_t)(m0 + row) * HH + k0 + kc, &sAh[chunk * 512]);
            load_lds16(Bh + (size_t)(n0 + row) * HH + k0 + kc, &sBh[chunk * 512]);
            if constexpr (TERMS == 3) {
                load_lds16(Al + (size_t)(m0 + row) * HH + k0 + kc, &sAl[chunk * 512]);
                load_lds16(Bl + (size_t)(n0 + row) * HH + k0 + kc, &sBl[chunk * 512]);
            }
        }
        __syncthreads();

        short8 aH[4], bH[4], aL[4], bL[4];
        #pragma unroll
        for (int i = 0; i < 4; ++i) {
            int ra = wr * 64 + i * 16 + (l & 15);
            int rb = wc * 64 + i * 16 + (l & 15);
            aH[i] = *(const short8*)&sAh[ra * 32 + (l >> 4) * 8];
            bH[i] = *(const short8*)&sBh[rb * 32 + (l >> 4) * 8];
            if constexpr (TERMS == 3) {
                aL[i] = *(const short8*)&sAl[ra * 32 + (l >> 4) * 8];
                bL[i] = *(const short8*)&sBl[rb * 32 + (l >> 4) * 8];
            }
        }
        #pragma unroll
        for (int i = 0; i < 4; ++i)
            #pragma unroll
            for (int j = 0; j < 4; ++j) {
                acc[i][j] = mfma16(aH[i], bH[j], acc[i][j]);
                if constexpr (TERMS == 3) {
                    acc[i][j] = mfma16(aH[i], bL[j], acc[i][j]);
                    acc[i][j] = mfma16(aL[i], bH[j], acc[i][j]);
                }
            }
        __syncthreads();
    }

    #pragma unroll
    for (int i = 0; i < 4; ++i) {
        int row = m0 + wr * 64 + i * 16 + ((l >> 4) << 2);
        #pragma unroll
        for (int j = 0; j < 4; ++j) {
            int col = n0 + wc * 64 + j * 16 + (l & 15);
            float bv = bias[col];
            #pragma unroll
            for (int r = 0; r < 4; ++r) {
                float cv = acc[i][j][r] + bv;
                size_t o = (size_t)(row + r) * Ntot + col;
                ushort_t h = f2bf(cv);
                Oh[o] = h;
                if constexpr (SPLIT_OUT) Ol[o] = f2bf(cv - bf2f(h));
            }
        }
    }
}

// ---------------- V transpose: [MM][128] -> [128][MM] ----------------
__global__ __launch_bounds__(256) void k_transpose_v(const ushort_t* __restrict__ V,
                                                     ushort_t* __restrict__ Vt) {
    __shared__ ushort_t t[64][72];   // +8 pad
    const int tid = threadIdx.x;
    const int bx = blockIdx.x;       // MM/64
    const int by = blockIdx.y;       // 128/64
    int r = tid >> 2, cg = (tid & 3) * 16;
    const ushort_t* src = &V[(size_t)(bx * 64 + r) * DD + by * 64 + cg];
    short8 v0 = *(const short8*)src;
    short8 v1 = *(const short8*)(src + 8);
    *(short8*)&t[r][cg] = v0;
    *(short8*)&t[r][cg + 8] = v1;
    __syncthreads();
    short8 o0, o1;
    #pragma unroll
    for (int j = 0; j < 8; ++j) { o0[j] = t[cg + j][r]; o1[j] = t[cg + 8 + j][r]; }
    ushort_t* dst = &Vt[(size_t)(by * 64 + r) * MM + bx * 64 + cg];
    *(short8*)dst = o0;
    *(short8*)(dst + 8) = o1;
}

// ---------------- flash attention ----------------
// grid (S/64, N, B), 256 thr = 4 waves, each wave owns 16 q-rows.
// Q [MM][ND] split bf16 (col = n*128+d); K [MM][128] split; Vt [128][MM]; Out [B][N][S][D] f32.
// All LDS tiles XOR-swizzled: elem_col ^= ((row&7)<<3)  (16B-block granular, bank-spread).
__global__ __launch_bounds__(256) void k_attn(
    const ushort_t* __restrict__ Qh, const ushort_t* __restrict__ Ql,
    const ushort_t* __restrict__ Kh, const ushort_t* __restrict__ Kl,
    const ushort_t* __restrict__ Vt, float* __restrict__ Out) {

    __shared__ ushort_t sKh[KVB * 128];     // [t][128] swizzled
    __shared__ ushort_t sKl[KVB * 128];
    __shared__ ushort_t sVt[128 * KVB];     // [d][KVB] swizzled
    __shared__ ushort_t sP[4 * 16 * KVB];   // per-wave [16][KVB] swizzled

    const int tid = threadIdx.x;
    const int w = tid >> 6, l = tid & 63;
    const int lg = l >> 4, li = l & 15;
    const int q0 = blockIdx.x * 64;
    const int n = blockIdx.y, b = blockIdx.z;

    // Q fragments in registers for the whole kernel: rows q0 + w*16 + li
    short8 qH[4], qL[4];
    {
        size_t base = ((size_t)(b * SS + q0 + w * 16 + li)) * ND + n * 128 + lg * 8;
        #pragma unroll
        for (int kk = 0; kk < 4; ++kk) {
            qH[kk] = *(const short8*)&Qh[base + kk * 32];
            qL[kk] = *(const short8*)&Ql[base + kk * 32];
        }
    }

    f32x4 accO[8] = {};
    float m[4] = {-3.0e38f, -3.0e38f, -3.0e38f, -3.0e38f};
    float lsum[4] = {0.f, 0.f, 0.f, 0.f};
    ushort_t* sPw = &sP[w * 16 * KVB];

    for (int t0 = 0; t0 < SS; t0 += KVB) {
        // ---- stage K hi/lo (64x128, 16KB each): linear LDS dest, pre-swizzled source
        #pragma unroll
        for (int c = 0; c < 4; ++c) {
            int seg = c * 4 + w;
            int oe = seg * 512 + l * 8;                 // elem offset in tile
            int row = oe >> 7;
            int ce = (oe & 127) ^ ((row & 7) << 3);
            size_t g = (size_t)(b * SS + t0 + row) * DD + ce;
            load_lds16(Kh + g, &sKh[seg * 512]);
            load_lds16(Kl + g, &sKl[seg * 512]);
        }
        // ---- stage Vt (128 x KVB, 16KB)
        #pragma unroll
        for (int c = 0; c < 4; ++c) {
            int seg = c * 4 + w;
            int oe = seg * 512 + l * 8;
            int row = oe >> 6;                          // d
            int ce = (oe & 63) ^ ((row & 7) << 3);
            size_t g = (size_t)row * MM + b * SS + t0 + ce;
            load_lds16(Vt + g, &sVt[seg * 512]);
        }
        __syncthreads();

        // ---- QK^T (3-term split => f32-accurate logits)
        f32x4 s[4] = {};
        #pragma unroll
        for (int ts = 0; ts < 4; ++ts) {
            int trow = ts * 16 + li;
            int sw = (trow & 7) << 3;
            #pragma unroll
            for (int kk = 0; kk < 4; ++kk) {
                int ce = (kk * 32 + lg * 8) ^ sw;
                short8 kH = *(const short8*)&sKh[trow * 128 + ce];
                short8 kL = *(const short8*)&sKl[trow * 128 + ce];
                s[ts] = mfma16(qH[kk], kH, s[ts]);
                s[ts] = mfma16(qH[kk], kL, s[ts]);
                s[ts] = mfma16(qL[kk], kH, s[ts]);
            }
        }

        // ---- online softmax (row q = lg*4 + r spread over 16 lanes)
        float p[4][4], scl[4];
        #pragma unroll
        for (int r = 0; r < 4; ++r) {
            float v = fmaxf(fmaxf(s[0][r], s[1][r]), fmaxf(s[2][r], s[3][r]));
            #pragma unroll
            for (int off = 8; off >= 1; off >>= 1) v = fmaxf(v, __shfl_xor(v, off, 16));
            float mn = fmaxf(m[r], v);
            scl[r] = __expf(m[r] - mn);
            float rs = 0.f;
            #pragma unroll
            for (int ts = 0; ts < 4; ++ts) {
                p[ts][r] = __expf(s[ts][r] - mn);
                rs += p[ts][r];
            }
            #pragma unroll
            for (int off = 8; off >= 1; off >>= 1) rs += __shfl_xor(rs, off, 16);
            lsum[r] = lsum[r] * scl[r] + rs;
            m[r] = mn;
        }
        #pragma unroll
        for (int db = 0; db < 8; ++db)
            #pragma unroll
            for (int r = 0; r < 4; ++r) accO[db][r] *= scl[r];

        // ---- P -> per-wave LDS (swizzled); wave-local, no block barrier needed
        #pragma unroll
        for (int ts = 0; ts < 4; ++ts)
            #pragma unroll
            for (int r = 0; r < 4; ++r) {
                int q = lg * 4 + r;
                int t = ts * 16 + li;
                sPw[q * KVB + (t ^ ((q & 7) << 3))] = f2bf(p[ts][r]);
            }
        asm volatile("s_waitcnt lgkmcnt(0)" ::: "memory");
        __builtin_amdgcn_sched_barrier(0);

        // ---- PV
        #pragma unroll
        for (int ks = 0; ks < 2; ++ks) {
            short8 pa = *(const short8*)&sPw[li * KVB + ((ks * 32 + lg * 8) ^ ((li & 7) << 3))];
            #pragma unroll
            for (int db = 0; db < 8; ++db) {
                int d = db * 16 + li;
                short8 vb = *(const short8*)&sVt[d * KVB + ((ks * 32 + lg * 8) ^ ((d & 7) << 3))];
                accO[db] = mfma16(pa, vb, accO[db]);
            }
        }
        __syncthreads();
    }

    // ---- epilogue: normalize, write f32 [B][N][S][D]
    #pragma unroll
    for (int r = 0; r < 4; ++r) {
        float inv = 1.0f / lsum[r];
        int q = q0 + w * 16 + lg * 4 + r;
        size_t base = (((size_t)b * NH + n) * SS + q) * DD;
        #pragma unroll
        for (int db = 0; db < 8; ++db)
            Out[base + db * 16 + li] = accO[db][r] * inv;
    }
}

// ---------------- workspace layout (bytes) ----------------
#define OFF_HHI   ((size_t)0)
#define OFF_HLO   (OFF_HHI + (size_t)MM*HH*2)
#define OFF_WQTH  (OFF_HLO + (size_t)MM*HH*2)
#define OFF_WQTL  (OFF_WQTH + (size_t)ND*HH*2)
#define OFF_WKTH  (OFF_WQTL + (size_t)ND*HH*2)
#define OFF_WKTL  (OFF_WKTH + (size_t)DD*HH*2)
#define OFF_WVTH  (OFF_WKTL + (size_t)DD*HH*2)
#define OFF_QHI   (OFF_WVTH + (size_t)DD*HH*2)
#define OFF_QLO   (OFF_QHI + (size_t)MM*ND*2)
#define OFF_KHI   (OFF_QLO + (size_t)MM*ND*2)
#define OFF_KLO   (OFF_KHI + (size_t)MM*DD*2)
#define OFF_VBF   (OFF_KLO + (size_t)MM*DD*2)
// Vt aliases the (dead after Q-GEMM) Wq^T-hi region; stream order makes this safe.
#define OFF_VT    OFF_WQTH

extern "C" void kernel_launch(void* const* d_in, const int* in_sizes, int n_in,
                              void* d_out, int out_size, void* d_ws, size_t ws_size,
                              hipStream_t stream) {
    const float* hs = (const float*)d_in[0];
    const float* Wq = (const float*)d_in[1];
    const float* bq = (const float*)d_in[2];
    const float* Wk = (const float*)d_in[3];
    const float* bk = (const float*)d_in[4];
    const float* Wv = (const float*)d_in[5];
    const float* bv = (const float*)d_in[6];
    float* out = (float*)d_out;
    char* ws = (char*)d_ws;

    ushort_t* hhi  = (ushort_t*)(ws + OFF_HHI);
    ushort_t* hlo  = (ushort_t*)(ws + OFF_HLO);
    ushort_t* wqth = (ushort_t*)(ws + OFF_WQTH);
    ushort_t* wqtl = (ushort_t*)(ws + OFF_WQTL);
    ushort_t* wkth = (ushort_t*)(ws + OFF_WKTH);
    ushort_t* wktl = (ushort_t*)(ws + OFF_WKTL);
    ushort_t* wvth = (ushort_t*)(ws + OFF_WVTH);
    ushort_t* qhi  = (ushort_t*)(ws + OFF_QHI);
    ushort_t* qlo  = (ushort_t*)(ws + OFF_QLO);
    ushort_t* khi  = (ushort_t*)(ws + OFF_KHI);
    ushort_t* klo  = (ushort_t*)(ws + OFF_KLO);
    ushort_t* vbf  = (ushort_t*)(ws + OFF_VBF);
    ushort_t* vt   = (ushort_t*)(ws + OFF_VT);

    // prep
    k_split<<<(MM*HH)/(256*4), 256, 0, stream>>>(hs, hhi, hlo, MM*HH);
    k_prep_w<<<(ND*HH + 255)/256, 256, 0, stream>>>(Wq, wqth, wqtl, NH, HH, DD);
    k_prep_w<<<(HH*DD + 255)/256, 256, 0, stream>>>(Wk, wkth, wktl, 1, HH, DD);
    k_prep_w<<<(HH*DD + 255)/256, 256, 0, stream>>>(Wv, wvth, nullptr, 1, HH, DD);

    // projections: Q as one 4096x2048x2048 GEMM; K/V 4096x2048x128
    dim3 gq(MM/128, ND/128);
    k_gemm<3, true><<<gq, 256, 0, stream>>>(hhi, hlo, wqth, wqtl, bq, qhi, qlo, ND);
    dim3 gk(MM/128, 1);
    k_gemm<3, true><<<gk, 256, 0, stream>>>(hhi, hlo, wkth, wktl, bk, khi, klo, DD);
    k_gemm<1, false><<<gk, 256, 0, stream>>>(hhi, nullptr, wvth, nullptr, bv, vbf, nullptr, DD);

    // V transpose (after Q-GEMM: vt aliases wqth)
    dim3 gt(MM/64, 2);
    k_transpose_v<<<gt, 256, 0, stream>>>(vbf, vt);

    // attention
    dim3 ga(SS/64, NH, NB);
    k_attn<<<ga, 256, 0, stream>>>(qhi, qlo, khi, klo, vt, out);
}

// Round 4
// 176.508 us; speedup vs baseline: 2.8793x; 2.0262x over previous
//
#include <hip/hip_runtime.h>
#include <hip/hip_bf16.h>

typedef unsigned short ushort_t;
typedef _Float16 half_t;
typedef __attribute__((ext_vector_type(8))) _Float16 h8;     // 8 fp16 (MFMA A/B frag)
typedef __attribute__((ext_vector_type(8))) short short8;
typedef __attribute__((ext_vector_type(4))) float f32x4;
typedef __attribute__((ext_vector_type(4))) float f4;

#define NB 4
#define SS 1024
#define HH 2048
#define NH 16
#define DD 128
#define MM (NB*SS)          // 4096 rows
#define NTOT 2304           // 2048 Q cols | 128 K | 128 V
#define COL_K 2048
#define COL_V 2176
#define KVB 64

__device__ __forceinline__ ushort_t f2h(float x) {
    half_t h = (half_t)x;
    return *(ushort_t*)&h;
}
__device__ __forceinline__ f32x4 mfma16h(h8 a, h8 b, f32x4 c) {
    return __builtin_amdgcn_mfma_f32_16x16x32_f16(a, b, c, 0, 0, 0);
}
__device__ __forceinline__ void load_lds16(const ushort_t* g, ushort_t* l) {
    __builtin_amdgcn_global_load_lds(
        (const __attribute__((address_space(1))) unsigned int*)g,
        (__attribute__((address_space(3))) unsigned int*)l,
        16, 0, 0);
}

// ---------------- f32 -> fp16 convert (hidden states) ----------------
__global__ void k_cvt(const float* __restrict__ src, ushort_t* __restrict__ dst, int n) {
    int i = (blockIdx.x * blockDim.x + threadIdx.x) * 8;
    if (i + 7 < n) {
        f4 a = *(const f4*)(src + i);
        f4 b = *(const f4*)(src + i + 4);
        short8 o;
        #pragma unroll
        for (int j = 0; j < 4; ++j) { o[j] = (short)f2h(a[j]); o[4 + j] = (short)f2h(b[j]); }
        *(short8*)(dst + i) = o;
    }
}

// ---------------- tiled weight transpose+convert: W[n][H][Dd] -> T[n*Dd+d][HH] ----------------
__global__ __launch_bounds__(256) void k_tw(const float* __restrict__ W,
                                            ushort_t* __restrict__ T, int Dd) {
    __shared__ ushort_t t[64][74];
    const int n = blockIdx.z;
    const int h0 = blockIdx.x * 64, d0 = blockIdx.y * 64;
    const int r = threadIdx.x >> 2, cg = (threadIdx.x & 3) * 16;
    const float* src = W + ((size_t)n * HH + h0 + r) * Dd + d0 + cg;
    #pragma unroll
    for (int v = 0; v < 4; ++v) {
        f4 a = *(const f4*)(src + v * 4);
        #pragma unroll
        for (int j = 0; j < 4; ++j) t[r][cg + v * 4 + j] = f2h(a[j]);
    }
    __syncthreads();
    short8 o0, o1;
    #pragma unroll
    for (int j = 0; j < 8; ++j) { o0[j] = (short)t[cg + j][r]; o1[j] = (short)t[cg + 8 + j][r]; }
    ushort_t* dst = T + ((size_t)(n * Dd + d0 + r)) * HH + h0 + cg;
    *(short8*)dst = o0;
    *(short8*)(dst + 8) = o1;
}

// ---------------- bias concat [2304] ----------------
__global__ void k_bias(const float* __restrict__ bq, const float* __restrict__ bk,
                       const float* __restrict__ bv, float* __restrict__ bc) {
    int i = blockIdx.x * 256 + threadIdx.x;
    if (i < NTOT)
        bc[i] = (i < COL_K) ? bq[i] : ((i < COL_V) ? bk[i - COL_K] : bv[i - COL_V]);
}

// ---------------- fp16 GEMM: O[M][NTOT] = A[M][HH] * B[NTOT][HH]^T + bias ----------------
// grid 576 (1-D, XCD-swizzled): 32 m-tiles x 18 n-tiles of 128x128.
__global__ __launch_bounds__(256) void k_gemm(
    const ushort_t* __restrict__ A, const ushort_t* __restrict__ B,
    const float* __restrict__ bias, ushort_t* __restrict__ O) {

    constexpr int BK = 32;
    __shared__ ushort_t sA[128 * BK], sB[128 * BK];

    const int bid = blockIdx.x;
    const int swz = (bid & 7) * 72 + (bid >> 3);     // 576/8 = 72 per XCD, bijective
    const int m0 = (swz & 31) * 128;
    const int n0 = (swz >> 5) * 128;

    const int tid = threadIdx.x;
    const int w = tid >> 6, l = tid & 63;
    const int wr = w >> 1, wc = w & 1;
    f32x4 acc[4][4] = {};

    for (int kt = 0; kt < HH / BK; ++kt) {
        const int k0 = kt * BK;
        #pragma unroll
        for (int c = 0; c < 2; ++c) {
            int chunk = c * 4 + w;
            int idx = chunk * 512 + l * 8;
            int row = idx >> 5, kc = idx & 31;
            load_lds16(A + (size_t)(m0 + row) * HH + k0 + kc, &sA[chunk * 512]);
            load_lds16(B + (size_t)(n0 + row) * HH + k0 + kc, &sB[chunk * 512]);
        }
        __syncthreads();

        h8 a[4], b[4];
        #pragma unroll
        for (int i = 0; i < 4; ++i) {
            int ra = wr * 64 + i * 16 + (l & 15);
            int rb = wc * 64 + i * 16 + (l & 15);
            a[i] = *(const h8*)&sA[ra * 32 + (l >> 4) * 8];
            b[i] = *(const h8*)&sB[rb * 32 + (l >> 4) * 8];
        }
        #pragma unroll
        for (int i = 0; i < 4; ++i)
            #pragma unroll
            for (int j = 0; j < 4; ++j)
                acc[i][j] = mfma16h(a[i], b[j], acc[i][j]);
        __syncthreads();
    }

    #pragma unroll
    for (int i = 0; i < 4; ++i) {
        int row = m0 + wr * 64 + i * 16 + ((l >> 4) << 2);
        #pragma unroll
        for (int j = 0; j < 4; ++j) {
            int col = n0 + wc * 64 + j * 16 + (l & 15);
            float bv = bias[col];
            #pragma unroll
            for (int r = 0; r < 4; ++r) {
                float cv = acc[i][j][r] + bv;
                O[(size_t)(row + r) * NTOT + col] = f2h(cv);
            }
        }
    }
}

// ---------------- V transpose: O cols [COL_V..COL_V+128) -> Vt[128][MM] ----------------
__global__ __launch_bounds__(256) void k_transpose_v(const ushort_t* __restrict__ O,
                                                     ushort_t* __restrict__ Vt) {
    __shared__ ushort_t t[64][74];
    const int tid = threadIdx.x;
    const int bx = blockIdx.x;       // MM/64
    const int by = blockIdx.y;       // 128/64
    int r = tid >> 2, cg = (tid & 3) * 16;
    const ushort_t* src = &O[(size_t)(bx * 64 + r) * NTOT + COL_V + by * 64 + cg];
    short8 v0 = *(const short8*)src;
    short8 v1 = *(const short8*)(src + 8);
    #pragma unroll
    for (int j = 0; j < 8; ++j) { t[r][cg + j] = (ushort_t)v0[j]; t[r][cg + 8 + j] = (ushort_t)v1[j]; }
    __syncthreads();
    short8 o0, o1;
    #pragma unroll
    for (int j = 0; j < 8; ++j) { o0[j] = (short)t[cg + j][r]; o1[j] = (short)t[cg + 8 + j][r]; }
    ushort_t* dst = &Vt[(size_t)(by * 64 + r) * MM + bx * 64 + cg];
    *(short8*)dst = o0;
    *(short8*)(dst + 8) = o1;
}

// ---------------- flash attention (fp16 single-term) ----------------
// grid (S/64, N, B), 256 thr = 4 waves, each wave owns 16 q-rows.
// Q/K from O [MM][NTOT] (Q at col n*128, K at COL_K); Vt [128][MM]; Out [B][N][S][D] f32.
__global__ __launch_bounds__(256) void k_attn(
    const ushort_t* __restrict__ O, const ushort_t* __restrict__ Vt,
    float* __restrict__ Out) {

    __shared__ ushort_t sK[KVB * 128];      // [t][128] swizzled
    __shared__ ushort_t sVt[128 * KVB];     // [d][KVB] swizzled
    __shared__ ushort_t sP[4 * 16 * KVB];   // per-wave [16][KVB] swizzled

    const int tid = threadIdx.x;
    const int w = tid >> 6, l = tid & 63;
    const int lg = l >> 4, li = l & 15;
    const int q0 = blockIdx.x * 64;
    const int n = blockIdx.y, b = blockIdx.z;

    // Q fragments in registers: rows q0 + w*16 + li
    h8 qv[4];
    {
        size_t base = ((size_t)(b * SS + q0 + w * 16 + li)) * NTOT + n * 128 + lg * 8;
        #pragma unroll
        for (int kk = 0; kk < 4; ++kk)
            qv[kk] = *(const h8*)&O[base + kk * 32];
    }

    f32x4 accO[8] = {};
    float m[4] = {-3.0e38f, -3.0e38f, -3.0e38f, -3.0e38f};
    float lsum[4] = {0.f, 0.f, 0.f, 0.f};
    ushort_t* sPw = &sP[w * 16 * KVB];

    for (int t0 = 0; t0 < SS; t0 += KVB) {
        // ---- stage K (64x128 fp16, 16KB): linear LDS dest, pre-swizzled source
        #pragma unroll
        for (int c = 0; c < 4; ++c) {
            int seg = c * 4 + w;
            int oe = seg * 512 + l * 8;
            int row = oe >> 7;
            int ce = (oe & 127) ^ ((row & 7) << 3);
            size_t g = (size_t)(b * SS + t0 + row) * NTOT + COL_K + ce;
            load_lds16(O + g, &sK[seg * 512]);
        }
        // ---- stage Vt (128 x KVB, 16KB)
        #pragma unroll
        for (int c = 0; c < 4; ++c) {
            int seg = c * 4 + w;
            int oe = seg * 512 + l * 8;
            int row = oe >> 6;                          // d
            int ce = (oe & 63) ^ ((row & 7) << 3);
            size_t g = (size_t)row * MM + b * SS + t0 + ce;
            load_lds16(Vt + g, &sVt[seg * 512]);
        }
        __syncthreads();

        // ---- QK^T (fp16, single term)
        f32x4 s[4] = {};
        #pragma unroll
        for (int ts = 0; ts < 4; ++ts) {
            int trow = ts * 16 + li;
            int sw = (trow & 7) << 3;
            #pragma unroll
            for (int kk = 0; kk < 4; ++kk) {
                int ce = (kk * 32 + lg * 8) ^ sw;
                h8 kv = *(const h8*)&sK[trow * 128 + ce];
                s[ts] = mfma16h(qv[kk], kv, s[ts]);
            }
        }

        // ---- online softmax (row q = lg*4 + r spread over 16 lanes)
        float p[4][4], scl[4];
        #pragma unroll
        for (int r = 0; r < 4; ++r) {
            float v = fmaxf(fmaxf(s[0][r], s[1][r]), fmaxf(s[2][r], s[3][r]));
            #pragma unroll
            for (int off = 8; off >= 1; off >>= 1) v = fmaxf(v, __shfl_xor(v, off, 16));
            float mn = fmaxf(m[r], v);
            scl[r] = __expf(m[r] - mn);
            float rs = 0.f;
            #pragma unroll
            for (int ts = 0; ts < 4; ++ts) {
                p[ts][r] = __expf(s[ts][r] - mn);
                rs += p[ts][r];
            }
            #pragma unroll
            for (int off = 8; off >= 1; off >>= 1) rs += __shfl_xor(rs, off, 16);
            lsum[r] = lsum[r] * scl[r] + rs;
            m[r] = mn;
        }
        #pragma unroll
        for (int db = 0; db < 8; ++db)
            #pragma unroll
            for (int r = 0; r < 4; ++r) accO[db][r] *= scl[r];

        // ---- P -> per-wave LDS (fp16, swizzled); wave-local
        #pragma unroll
        for (int ts = 0; ts < 4; ++ts)
            #pragma unroll
            for (int r = 0; r < 4; ++r) {
                int q = lg * 4 + r;
                int t = ts * 16 + li;
                sPw[q * KVB + (t ^ ((q & 7) << 3))] = f2h(p[ts][r]);
            }
        asm volatile("s_waitcnt lgkmcnt(0)" ::: "memory");
        __builtin_amdgcn_sched_barrier(0);

        // ---- PV
        #pragma unroll
        for (int ks = 0; ks < 2; ++ks) {
            h8 pa = *(const h8*)&sPw[li * KVB + ((ks * 32 + lg * 8) ^ ((li & 7) << 3))];
            #pragma unroll
            for (int db = 0; db < 8; ++db) {
                int d = db * 16 + li;
                h8 vb = *(const h8*)&sVt[d * KVB + ((ks * 32 + lg * 8) ^ ((d & 7) << 3))];
                accO[db] = mfma16h(pa, vb, accO[db]);
            }
        }
        __syncthreads();
    }

    // ---- epilogue: normalize, write f32 [B][N][S][D]
    #pragma unroll
    for (int r = 0; r < 4; ++r) {
        float inv = 1.0f / lsum[r];
        int q = q0 + w * 16 + lg * 4 + r;
        size_t base = (((size_t)b * NH + n) * SS + q) * DD;
        #pragma unroll
        for (int db = 0; db < 8; ++db)
            Out[base + db * 16 + li] = accO[db][r] * inv;
    }
}

// ---------------- workspace layout (bytes) ----------------
#define OFF_HC    ((size_t)0)                          // hidden fp16 [MM][HH]
#define OFF_BC    (OFF_HC + (size_t)MM*HH*2)           // Bcat fp16 [NTOT][HH]
#define OFF_BIAS  (OFF_BC + (size_t)NTOT*HH*2)         // bias f32 [NTOT] = 9216 B
#define OFF_O     (OFF_BIAS + (size_t)16384)           // FIX: was 4096 (< NTOT*4) -> bias aliased O
#define OFF_VT    (OFF_O + (size_t)MM*NTOT*2)          // Vt fp16 [128][MM]

extern "C" void kernel_launch(void* const* d_in, const int* in_sizes, int n_in,
                              void* d_out, int out_size, void* d_ws, size_t ws_size,
                              hipStream_t stream) {
    const float* hs = (const float*)d_in[0];
    const float* Wq = (const float*)d_in[1];
    const float* bq = (const float*)d_in[2];
    const float* Wk = (const float*)d_in[3];
    const float* bk = (const float*)d_in[4];
    const float* Wv = (const float*)d_in[5];
    const float* bv = (const float*)d_in[6];
    float* out = (float*)d_out;
    char* ws = (char*)d_ws;

    ushort_t* hc   = (ushort_t*)(ws + OFF_HC);
    ushort_t* bcat = (ushort_t*)(ws + OFF_BC);
    float*    bias = (float*)(ws + OFF_BIAS);
    ushort_t* Obuf = (ushort_t*)(ws + OFF_O);
    ushort_t* vt   = (ushort_t*)(ws + OFF_VT);

    // prep
    k_cvt<<<(MM*HH)/(256*8), 256, 0, stream>>>(hs, hc, MM*HH);
    dim3 gwq(HH/64, DD/64, NH);
    k_tw<<<gwq, 256, 0, stream>>>(Wq, bcat, DD);
    dim3 gwk(HH/64, DD/64, 1);
    k_tw<<<gwk, 256, 0, stream>>>(Wk, bcat + (size_t)COL_K*HH, DD);
    k_tw<<<gwk, 256, 0, stream>>>(Wv, bcat + (size_t)COL_V*HH, DD);
    k_bias<<<(NTOT + 255)/256, 256, 0, stream>>>(bq, bk, bv, bias);

    // merged projection GEMM: 4096 x 2304 x 2048
    k_gemm<<<(MM/128)*(NTOT/128), 256, 0, stream>>>(hc, bcat, bias, Obuf);

    // V transpose
    dim3 gt(MM/64, DD/64);
    k_transpose_v<<<gt, 256, 0, stream>>>(Obuf, vt);

    // attention
    dim3 ga(SS/64, NH, NB);
    k_attn<<<ga, 256, 0, stream>>>(Obuf, vt, out);
}

// Round 5
// 155.744 us; speedup vs baseline: 3.2632x; 1.1333x over previous
//
#include <hip/hip_runtime.h>
#include <hip/hip_bf16.h>

typedef unsigned short ushort_t;
typedef _Float16 half_t;
typedef __attribute__((ext_vector_type(8))) _Float16 h8;     // 8 fp16 (K=32 MFMA A/B frag)
typedef __attribute__((ext_vector_type(4))) _Float16 h4;     // 4 fp16 (K=16 MFMA A/B frag)
typedef __attribute__((ext_vector_type(8))) short short8;
typedef __attribute__((ext_vector_type(4))) float f32x4;
typedef __attribute__((ext_vector_type(4))) float f4;

#define NB 4
#define SS 1024
#define HH 2048
#define NH 16
#define DD 128
#define MM (NB*SS)          // 4096 rows
#define NTOT 2304           // 2048 Q cols | 128 K | 128 V
#define COL_K 2048
#define COL_V 2176
#define KVB 64
#define L2E 1.44269504089f

__device__ __forceinline__ ushort_t f2h(float x) {
    half_t h = (half_t)x;
    return *(ushort_t*)&h;
}
__device__ __forceinline__ f32x4 mfma16h(h8 a, h8 b, f32x4 c) {
    return __builtin_amdgcn_mfma_f32_16x16x32_f16(a, b, c, 0, 0, 0);
}
__device__ __forceinline__ void load_lds16(const ushort_t* g, ushort_t* l) {
    __builtin_amdgcn_global_load_lds(
        (const __attribute__((address_space(1))) unsigned int*)g,
        (__attribute__((address_space(3))) unsigned int*)l,
        16, 0, 0);
}

// ---------------- f32 -> fp16 convert (hidden states) ----------------
__global__ void k_cvt(const float* __restrict__ src, ushort_t* __restrict__ dst, int n) {
    int i = (blockIdx.x * blockDim.x + threadIdx.x) * 8;
    if (i + 7 < n) {
        f4 a = *(const f4*)(src + i);
        f4 b = *(const f4*)(src + i + 4);
        short8 o;
        #pragma unroll
        for (int j = 0; j < 4; ++j) { o[j] = (short)f2h(a[j]); o[4 + j] = (short)f2h(b[j]); }
        *(short8*)(dst + i) = o;
    }
}

// ---------------- tiled weight transpose+convert: W[n][H][Dd] -> T[n*Dd+d][HH] ----------------
__global__ __launch_bounds__(256) void k_tw(const float* __restrict__ W,
                                            ushort_t* __restrict__ T, int Dd) {
    __shared__ ushort_t t[64][74];
    const int n = blockIdx.z;
    const int h0 = blockIdx.x * 64, d0 = blockIdx.y * 64;
    const int r = threadIdx.x >> 2, cg = (threadIdx.x & 3) * 16;
    const float* src = W + ((size_t)n * HH + h0 + r) * Dd + d0 + cg;
    #pragma unroll
    for (int v = 0; v < 4; ++v) {
        f4 a = *(const f4*)(src + v * 4);
        #pragma unroll
        for (int j = 0; j < 4; ++j) t[r][cg + v * 4 + j] = f2h(a[j]);
    }
    __syncthreads();
    short8 o0, o1;
    #pragma unroll
    for (int j = 0; j < 8; ++j) { o0[j] = (short)t[cg + j][r]; o1[j] = (short)t[cg + 8 + j][r]; }
    ushort_t* dst = T + ((size_t)(n * Dd + d0 + r)) * HH + h0 + cg;
    *(short8*)dst = o0;
    *(short8*)(dst + 8) = o1;
}

// ---------------- bias concat [2304] ----------------
__global__ void k_bias(const float* __restrict__ bq, const float* __restrict__ bk,
                       const float* __restrict__ bv, float* __restrict__ bc) {
    int i = blockIdx.x * 256 + threadIdx.x;
    if (i < NTOT)
        bc[i] = (i < COL_K) ? bq[i] : ((i < COL_V) ? bk[i - COL_K] : bv[i - COL_V]);
}

// ---------------- fp16 GEMM: O[M][NTOT] = A[M][HH] * B[NTOT][HH]^T + bias ----------------
__global__ __launch_bounds__(256) void k_gemm(
    const ushort_t* __restrict__ A, const ushort_t* __restrict__ B,
    const float* __restrict__ bias, ushort_t* __restrict__ O) {

    constexpr int BK = 32;
    __shared__ ushort_t sA[128 * BK], sB[128 * BK];

    const int bid = blockIdx.x;
    const int swz = (bid & 7) * 72 + (bid >> 3);     // 576/8 = 72 per XCD, bijective
    const int m0 = (swz & 31) * 128;
    const int n0 = (swz >> 5) * 128;

    const int tid = threadIdx.x;
    const int w = tid >> 6, l = tid & 63;
    const int wr = w >> 1, wc = w & 1;
    f32x4 acc[4][4] = {};

    for (int kt = 0; kt < HH / BK; ++kt) {
        const int k0 = kt * BK;
        #pragma unroll
        for (int c = 0; c < 2; ++c) {
            int chunk = c * 4 + w;
            int idx = chunk * 512 + l * 8;
            int row = idx >> 5, kc = idx & 31;
            load_lds16(A + (size_t)(m0 + row) * HH + k0 + kc, &sA[chunk * 512]);
            load_lds16(B + (size_t)(n0 + row) * HH + k0 + kc, &sB[chunk * 512]);
        }
        __syncthreads();

        h8 a[4], b[4];
        #pragma unroll
        for (int i = 0; i < 4; ++i) {
            int ra = wr * 64 + i * 16 + (l & 15);
            int rb = wc * 64 + i * 16 + (l & 15);
            a[i] = *(const h8*)&sA[ra * 32 + (l >> 4) * 8];
            b[i] = *(const h8*)&sB[rb * 32 + (l >> 4) * 8];
        }
        #pragma unroll
        for (int i = 0; i < 4; ++i)
            #pragma unroll
            for (int j = 0; j < 4; ++j)
                acc[i][j] = mfma16h(a[i], b[j], acc[i][j]);
        __syncthreads();
    }

    #pragma unroll
    for (int i = 0; i < 4; ++i) {
        int row = m0 + wr * 64 + i * 16 + ((l >> 4) << 2);
        #pragma unroll
        for (int j = 0; j < 4; ++j) {
            int col = n0 + wc * 64 + j * 16 + (l & 15);
            float bv = bias[col];
            #pragma unroll
            for (int r = 0; r < 4; ++r) {
                float cv = acc[i][j][r] + bv;
                O[(size_t)(row + r) * NTOT + col] = f2h(cv);
            }
        }
    }
}

// ---------------- V transpose: O cols [COL_V..COL_V+128) -> Vt[128][MM] ----------------
__global__ __launch_bounds__(256) void k_transpose_v(const ushort_t* __restrict__ O,
                                                     ushort_t* __restrict__ Vt) {
    __shared__ ushort_t t[64][74];
    const int tid = threadIdx.x;
    const int bx = blockIdx.x;       // MM/64
    const int by = blockIdx.y;       // 128/64
    int r = tid >> 2, cg = (tid & 3) * 16;
    const ushort_t* src = &O[(size_t)(bx * 64 + r) * NTOT + COL_V + by * 64 + cg];
    short8 v0 = *(const short8*)src;
    short8 v1 = *(const short8*)(src + 8);
    #pragma unroll
    for (int j = 0; j < 8; ++j) { t[r][cg + j] = (ushort_t)v0[j]; t[r][cg + 8 + j] = (ushort_t)v1[j]; }
    __syncthreads();
    short8 o0, o1;
    #pragma unroll
    for (int j = 0; j < 8; ++j) { o0[j] = (short)t[cg + j][r]; o1[j] = (short)t[cg + 8 + j][r]; }
    ushort_t* dst = &Vt[(size_t)(by * 64 + r) * MM + bx * 64 + cg];
    *(short8*)dst = o0;
    *(short8*)(dst + 8) = o1;
}

// ---------------- flash attention: swapped QK^T, in-register softmax ----------------
// grid (S/64, N, B), 4 waves x 16 q-rows. Per-lane: q = li, t-slices by lg.
// QK^T: S^T = mfma(K_frag, Q_frag) -> lane holds S[t=ts*16+lg*4+r][q=li].
// PV:   O^T = mfma_16x16x16(Vt_frag, P^T_frag) -> acc[db][r] = O[q=li][d=db*16+lg*4+r].
__global__ __launch_bounds__(256) void k_attn(
    const ushort_t* __restrict__ O, const ushort_t* __restrict__ Vt,
    float* __restrict__ Out) {

    __shared__ ushort_t sK[2][KVB * 128];     // [t][128] swizzled, double-buffered
    __shared__ ushort_t sVt[2][128 * KVB];    // [d][KVB] swizzled, double-buffered

    const int tid = threadIdx.x;
    const int w = tid >> 6, l = tid & 63;
    const int lg = l >> 4, li = l & 15;
    const int q0 = blockIdx.x * 64;
    const int n = blockIdx.y, b = blockIdx.z;

    // Q fragments in registers: row q = q0 + w*16 + li, d-chunk = kk*32 + lg*8
    h8 qv[4];
    {
        size_t base = ((size_t)(b * SS + q0 + w * 16 + li)) * NTOT + n * 128 + lg * 8;
        #pragma unroll
        for (int kk = 0; kk < 4; ++kk)
            qv[kk] = *(const h8*)&O[base + kk * 32];
    }

    f32x4 accO[8] = {};
    float m2 = -3.0e38f;     // running row-max * log2(e), per-lane (q = li)
    float lsum = 0.f;        // per-lane partial denominator

    auto stage = [&](int bi, int t0) {
        #pragma unroll
        for (int c = 0; c < 4; ++c) {
            int seg = c * 4 + w;
            int oe = seg * 512 + l * 8;
            int row = oe >> 7;
            int ce = (oe & 127) ^ ((row & 7) << 3);
            size_t g = (size_t)(b * SS + t0 + row) * NTOT + COL_K + ce;
            load_lds16(O + g, &sK[bi][seg * 512]);
        }
        #pragma unroll
        for (int c = 0; c < 4; ++c) {
            int seg = c * 4 + w;
            int oe = seg * 512 + l * 8;
            int row = oe >> 6;
            int ce = (oe & 63) ^ ((row & 7) << 3);
            size_t g = (size_t)row * MM + b * SS + t0 + ce;
            load_lds16(Vt + g, &sVt[bi][seg * 512]);
        }
    };

    stage(0, 0);
    constexpr int NT = SS / KVB;   // 16

    for (int it = 0; it < NT; ++it) {
        const int cur = it & 1;
        __syncthreads();                       // drains stage(cur); all waves past compute(cur^1)
        if (it + 1 < NT) stage(cur ^ 1, (it + 1) * KVB);
        const ushort_t* sKc = sK[cur];
        const ushort_t* sVc = sVt[cur];

        // ---- QK^T swapped: s[ts] holds S[t = ts*16 + lg*4 + r][q = li]
        f32x4 s[4] = {};
        #pragma unroll
        for (int ts = 0; ts < 4; ++ts) {
            int trow = ts * 16 + li;
            int sw = (trow & 7) << 3;
            #pragma unroll
            for (int kk = 0; kk < 4; ++kk) {
                h8 kv = *(const h8*)&sKc[trow * 128 + ((kk * 32 + lg * 8) ^ sw)];
                s[ts] = mfma16h(kv, qv[kk], s[ts]);   // A=K, B=Q -> S^T
            }
        }

        // ---- in-register online softmax (row q = li; 16 values per lane)
        float v = fmaxf(fmaxf(s[0][0], s[0][1]), fmaxf(s[0][2], s[0][3]));
        #pragma unroll
        for (int ts = 1; ts < 4; ++ts)
            v = fmaxf(v, fmaxf(fmaxf(s[ts][0], s[ts][1]), fmaxf(s[ts][2], s[ts][3])));
        v = fmaxf(v, __shfl_xor(v, 16));
        v = fmaxf(v, __shfl_xor(v, 32));
        float pm2 = v * L2E;

        // defer-max: only rescale when some row grew by > 8 (11.54 in log2)
        if (!__all(pm2 <= m2 + 11.54f)) {
            float m2n = fmaxf(m2, pm2);
            float scl = exp2f(m2 - m2n);
            lsum *= scl;
            #pragma unroll
            for (int db = 0; db < 8; ++db)
                #pragma unroll
                for (int r = 0; r < 4; ++r) accO[db][r] *= scl;
            m2 = m2n;
        }

        h4 pb[4];
        #pragma unroll
        for (int ts = 0; ts < 4; ++ts)
            #pragma unroll
            for (int r = 0; r < 4; ++r) {
                float p = exp2f(fmaf(s[ts][r], L2E, -m2));
                lsum += p;
                pb[ts][r] = (half_t)p;
            }

        // ---- PV: O^T = mfma_16x16x16(A = V^T frag, B = P^T frag)
        #pragma unroll
        for (int db = 0; db < 8; ++db) {
            int d = db * 16 + li;
            const ushort_t* vbase = &sVc[d * KVB];
            int sw = (d & 7) << 3;
            #pragma unroll
            for (int ts = 0; ts < 4; ++ts) {
                h4 va = *(const h4*)&vbase[(ts * 16 + lg * 4) ^ sw];
                accO[db] = __builtin_amdgcn_mfma_f32_16x16x16f16(va, pb[ts], accO[db], 0, 0, 0);
            }
        }
    }

    // ---- epilogue: finish denominator, normalize, write f32 [B][N][S][D]
    lsum += __shfl_xor(lsum, 16);
    lsum += __shfl_xor(lsum, 32);
    float inv = 1.0f / lsum;
    int q = q0 + w * 16 + li;
    size_t base = (((size_t)b * NH + n) * SS + q) * DD;
    #pragma unroll
    for (int db = 0; db < 8; ++db) {
        f4 o;
        #pragma unroll
        for (int r = 0; r < 4; ++r) o[r] = accO[db][r] * inv;
        *(f4*)&Out[base + db * 16 + lg * 4] = o;
    }
}

// ---------------- workspace layout (bytes) ----------------
#define OFF_HC    ((size_t)0)                          // hidden fp16 [MM][HH]
#define OFF_BC    (OFF_HC + (size_t)MM*HH*2)           // Bcat fp16 [NTOT][HH]
#define OFF_BIAS  (OFF_BC + (size_t)NTOT*HH*2)         // bias f32 [NTOT] = 9216 B
#define OFF_O     (OFF_BIAS + (size_t)16384)
#define OFF_VT    (OFF_O + (size_t)MM*NTOT*2)          // Vt fp16 [128][MM]

extern "C" void kernel_launch(void* const* d_in, const int* in_sizes, int n_in,
                              void* d_out, int out_size, void* d_ws, size_t ws_size,
                              hipStream_t stream) {
    const float* hs = (const float*)d_in[0];
    const float* Wq = (const float*)d_in[1];
    const float* bq = (const float*)d_in[2];
    const float* Wk = (const float*)d_in[3];
    const float* bk = (const float*)d_in[4];
    const float* Wv = (const float*)d_in[5];
    const float* bv = (const float*)d_in[6];
    float* out = (float*)d_out;
    char* ws = (char*)d_ws;

    ushort_t* hc   = (ushort_t*)(ws + OFF_HC);
    ushort_t* bcat = (ushort_t*)(ws + OFF_BC);
    float*    bias = (float*)(ws + OFF_BIAS);
    ushort_t* Obuf = (ushort_t*)(ws + OFF_O);
    ushort_t* vt   = (ushort_t*)(ws + OFF_VT);

    // prep
    k_cvt<<<(MM*HH)/(256*8), 256, 0, stream>>>(hs, hc, MM*HH);
    dim3 gwq(HH/64, DD/64, NH);
    k_tw<<<gwq, 256, 0, stream>>>(Wq, bcat, DD);
    dim3 gwk(HH/64, DD/64, 1);
    k_tw<<<gwk, 256, 0, stream>>>(Wk, bcat + (size_t)COL_K*HH, DD);
    k_tw<<<gwk, 256, 0, stream>>>(Wv, bcat + (size_t)COL_V*HH, DD);
    k_bias<<<(NTOT + 255)/256, 256, 0, stream>>>(bq, bk, bv, bias);

    // merged projection GEMM: 4096 x 2304 x 2048
    k_gemm<<<(MM/128)*(NTOT/128), 256, 0, stream>>>(hc, bcat, bias, Obuf);

    // V transpose
    dim3 gt(MM/64, DD/64);
    k_transpose_v<<<gt, 256, 0, stream>>>(Obuf, vt);

    // attention
    dim3 ga(SS/64, NH, NB);
    k_attn<<<ga, 256, 0, stream>>>(Obuf, vt, out);
}

// Round 6
// 154.558 us; speedup vs baseline: 3.2882x; 1.0077x over previous
//
#include <hip/hip_runtime.h>
#include <hip/hip_bf16.h>

typedef unsigned short ushort_t;
typedef _Float16 half_t;
typedef __attribute__((ext_vector_type(8))) _Float16 h8;     // 8 fp16 (K=32 MFMA A/B frag)
typedef __attribute__((ext_vector_type(8))) short short8;
typedef __attribute__((ext_vector_type(4))) float f32x4;
typedef __attribute__((ext_vector_type(4))) float f4;

#define NB 4
#define SS 1024
#define HH 2048
#define NH 16
#define DD 128
#define MM (NB*SS)          // 4096 rows
#define NTOT 2304           // 2048 Q cols | 128 K | 128 V
#define COL_K 2048
#define COL_V 2176
#define KVB 64
#define L2E 1.44269504089f

__device__ __forceinline__ ushort_t f2h(float x) {
    half_t h = (half_t)x;
    return *(ushort_t*)&h;
}
__device__ __forceinline__ f32x4 mfma16h(h8 a, h8 b, f32x4 c) {
    return __builtin_amdgcn_mfma_f32_16x16x32_f16(a, b, c, 0, 0, 0);
}
__device__ __forceinline__ void load_lds16(const ushort_t* g, ushort_t* l) {
    __builtin_amdgcn_global_load_lds(
        (const __attribute__((address_space(1))) unsigned int*)g,
        (__attribute__((address_space(3))) unsigned int*)l,
        16, 0, 0);
}

// ---------------- f32 -> fp16 convert (hidden states) ----------------
__global__ void k_cvt(const float* __restrict__ src, ushort_t* __restrict__ dst, int n) {
    int i = (blockIdx.x * blockDim.x + threadIdx.x) * 8;
    if (i + 7 < n) {
        f4 a = *(const f4*)(src + i);
        f4 b = *(const f4*)(src + i + 4);
        short8 o;
        #pragma unroll
        for (int j = 0; j < 4; ++j) { o[j] = (short)f2h(a[j]); o[4 + j] = (short)f2h(b[j]); }
        *(short8*)(dst + i) = o;
    }
}

// ---------------- tiled weight transpose+convert: W[n][H][Dd] -> T[n*Dd+d][HH] ----------------
__global__ __launch_bounds__(256) void k_tw(const float* __restrict__ W,
                                            ushort_t* __restrict__ T, int Dd) {
    __shared__ ushort_t t[64][74];
    const int n = blockIdx.z;
    const int h0 = blockIdx.x * 64, d0 = blockIdx.y * 64;
    const int r = threadIdx.x >> 2, cg = (threadIdx.x & 3) * 16;
    const float* src = W + ((size_t)n * HH + h0 + r) * Dd + d0 + cg;
    #pragma unroll
    for (int v = 0; v < 4; ++v) {
        f4 a = *(const f4*)(src + v * 4);
        #pragma unroll
        for (int j = 0; j < 4; ++j) t[r][cg + v * 4 + j] = f2h(a[j]);
    }
    __syncthreads();
    short8 o0, o1;
    #pragma unroll
    for (int j = 0; j < 8; ++j) { o0[j] = (short)t[cg + j][r]; o1[j] = (short)t[cg + 8 + j][r]; }
    ushort_t* dst = T + ((size_t)(n * Dd + d0 + r)) * HH + h0 + cg;
    *(short8*)dst = o0;
    *(short8*)(dst + 8) = o1;
}

// ---------------- bias concat [2304] ----------------
__global__ void k_bias(const float* __restrict__ bq, const float* __restrict__ bk,
                       const float* __restrict__ bv, float* __restrict__ bc) {
    int i = blockIdx.x * 256 + threadIdx.x;
    if (i < NTOT)
        bc[i] = (i < COL_K) ? bq[i] : ((i < COL_V) ? bk[i - COL_K] : bv[i - COL_V]);
}

// ---------------- fp16 GEMM: O[M][NTOT] = A[M][HH] * B[NTOT][HH]^T + bias ----------------
__global__ __launch_bounds__(256) void k_gemm(
    const ushort_t* __restrict__ A, const ushort_t* __restrict__ B,
    const float* __restrict__ bias, ushort_t* __restrict__ O) {

    constexpr int BK = 32;
    __shared__ ushort_t sA[128 * BK], sB[128 * BK];

    const int bid = blockIdx.x;
    const int swz = (bid & 7) * 72 + (bid >> 3);     // 576/8 = 72 per XCD, bijective
    const int m0 = (swz & 31) * 128;
    const int n0 = (swz >> 5) * 128;

    const int tid = threadIdx.x;
    const int w = tid >> 6, l = tid & 63;
    const int wr = w >> 1, wc = w & 1;
    f32x4 acc[4][4] = {};

    for (int kt = 0; kt < HH / BK; ++kt) {
        const int k0 = kt * BK;
        #pragma unroll
        for (int c = 0; c < 2; ++c) {
            int chunk = c * 4 + w;
            int idx = chunk * 512 + l * 8;
            int row = idx >> 5, kc = idx & 31;
            load_lds16(A + (size_t)(m0 + row) * HH + k0 + kc, &sA[chunk * 512]);
            load_lds16(B + (size_t)(n0 + row) * HH + k0 + kc, &sB[chunk * 512]);
        }
        __syncthreads();

        h8 a[4], b[4];
        #pragma unroll
        for (int i = 0; i < 4; ++i) {
            int ra = wr * 64 + i * 16 + (l & 15);
            int rb = wc * 64 + i * 16 + (l & 15);
            a[i] = *(const h8*)&sA[ra * 32 + (l >> 4) * 8];
            b[i] = *(const h8*)&sB[rb * 32 + (l >> 4) * 8];
        }
        #pragma unroll
        for (int i = 0; i < 4; ++i)
            #pragma unroll
            for (int j = 0; j < 4; ++j)
                acc[i][j] = mfma16h(a[i], b[j], acc[i][j]);
        __syncthreads();
    }

    #pragma unroll
    for (int i = 0; i < 4; ++i) {
        int row = m0 + wr * 64 + i * 16 + ((l >> 4) << 2);
        #pragma unroll
        for (int j = 0; j < 4; ++j) {
            int col = n0 + wc * 64 + j * 16 + (l & 15);
            float bv = bias[col];
            #pragma unroll
            for (int r = 0; r < 4; ++r) {
                float cv = acc[i][j][r] + bv;
                O[(size_t)(row + r) * NTOT + col] = f2h(cv);
            }
        }
    }
}

// ---------------- V transpose: O cols [COL_V..COL_V+128) -> Vt[128][MM] ----------------
__global__ __launch_bounds__(256) void k_transpose_v(const ushort_t* __restrict__ O,
                                                     ushort_t* __restrict__ Vt) {
    __shared__ ushort_t t[64][74];
    const int tid = threadIdx.x;
    const int bx = blockIdx.x;       // MM/64
    const int by = blockIdx.y;       // 128/64
    int r = tid >> 2, cg = (tid & 3) * 16;
    const ushort_t* src = &O[(size_t)(bx * 64 + r) * NTOT + COL_V + by * 64 + cg];
    short8 v0 = *(const short8*)src;
    short8 v1 = *(const short8*)(src + 8);
    #pragma unroll
    for (int j = 0; j < 8; ++j) { t[r][cg + j] = (ushort_t)v0[j]; t[r][cg + 8 + j] = (ushort_t)v1[j]; }
    __syncthreads();
    short8 o0, o1;
    #pragma unroll
    for (int j = 0; j < 8; ++j) { o0[j] = (short)t[cg + j][r]; o1[j] = (short)t[cg + 8 + j][r]; }
    ushort_t* dst = &Vt[(size_t)(by * 64 + r) * MM + bx * 64 + cg];
    *(short8*)dst = o0;
    *(short8*)(dst + 8) = o1;
}

// ---------------- flash attention: permuted-row swapped QK^T, K=32 PV, 32 q/wave ----------
// grid (S/128, N, B), 4 waves x 32 q-rows (2 halves of 16).
// QK^T A-rows permuted: trow = (ts&1)*32 + (li>>2)*8 + (ts>>1)*4 + (li&3), so lane (lg,li)
// reg r of s[qh][ts] = S[t = (ts&1)*32 + lg*8 + (ts>>1)*4 + r][q=li]. Concatenating
// p[ks][0..3] || p[2+ks][0..3] IS the K=32 PV B-fragment (t = ks*32 + lg*8 + e). No shuffles.
__global__ __launch_bounds__(256) void k_attn(
    const ushort_t* __restrict__ O, const ushort_t* __restrict__ Vt,
    float* __restrict__ Out) {

    __shared__ ushort_t sK[2][KVB * 128];     // [t][128], mask (t&3)|((t>>3)&1)<<2, dbuf
    __shared__ ushort_t sVt[2][128 * KVB];    // [d][KVB], mask d&7, dbuf

    const int tid = threadIdx.x;
    const int w = tid >> 6, l = tid & 63;
    const int lg = l >> 4, li = l & 15;
    const int q0 = blockIdx.x * 128;
    const int n = blockIdx.y, b = blockIdx.z;

    // Q fragments: half qh -> rows q0 + w*32 + qh*16 + li
    h8 qv[2][4];
    #pragma unroll
    for (int qh = 0; qh < 2; ++qh) {
        size_t base = ((size_t)(b * SS + q0 + w * 32 + qh * 16 + li)) * NTOT + n * 128 + lg * 8;
        #pragma unroll
        for (int kk = 0; kk < 4; ++kk)
            qv[qh][kk] = *(const h8*)&O[base + kk * 32];
    }

    f32x4 accO[2][8] = {};
    float m2[2] = {-3.0e38f, -3.0e38f};
    float lsum[2] = {0.f, 0.f};

    auto stage = [&](int bi, int t0) {
        #pragma unroll
        for (int c = 0; c < 4; ++c) {
            int seg = c * 4 + w;
            int oe = seg * 512 + l * 8;
            int row = oe >> 7;
            int mk = (row & 3) | (((row >> 3) & 1) << 2);
            int ce = (oe & 127) ^ (mk << 3);
            size_t g = (size_t)(b * SS + t0 + row) * NTOT + COL_K + ce;
            load_lds16(O + g, &sK[bi][seg * 512]);
        }
        #pragma unroll
        for (int c = 0; c < 4; ++c) {
            int seg = c * 4 + w;
            int oe = seg * 512 + l * 8;
            int row = oe >> 6;
            int ce = (oe & 63) ^ ((row & 7) << 3);
            size_t g = (size_t)row * MM + b * SS + t0 + ce;
            load_lds16(Vt + g, &sVt[bi][seg * 512]);
        }
    };

    stage(0, 0);
    constexpr int NT = SS / KVB;   // 16

    for (int it = 0; it < NT; ++it) {
        const int cur = it & 1;
        __syncthreads();                       // drains stage(cur)
        if (it + 1 < NT) stage(cur ^ 1, (it + 1) * KVB);
        const ushort_t* sKc = sK[cur];
        const ushort_t* sVc = sVt[cur];

        // ---- QK^T, permuted A-rows; kv shared across both q-halves
        f32x4 s[2][4] = {};
        #pragma unroll
        for (int ts = 0; ts < 4; ++ts) {
            int trow = (ts & 1) * 32 + ((li >> 2) << 3) + ((ts >> 1) << 2) + (li & 3);
            int mk = (trow & 3) | (((trow >> 3) & 1) << 2);
            #pragma unroll
            for (int kk = 0; kk < 4; ++kk) {
                h8 kv = *(const h8*)&sKc[trow * 128 + ((kk * 32 + lg * 8) ^ (mk << 3))];
                s[0][ts] = mfma16h(kv, qv[0][kk], s[0][ts]);
                s[1][ts] = mfma16h(kv, qv[1][kk], s[1][ts]);
            }
        }

        // ---- in-register online softmax per q-half; build K=32 PV B-frags directly
        h8 pb[2][2];
        #pragma unroll
        for (int qh = 0; qh < 2; ++qh) {
            float v = fmaxf(fmaxf(s[qh][0][0], s[qh][0][1]), fmaxf(s[qh][0][2], s[qh][0][3]));
            #pragma unroll
            for (int ts = 1; ts < 4; ++ts)
                v = fmaxf(v, fmaxf(fmaxf(s[qh][ts][0], s[qh][ts][1]),
                                   fmaxf(s[qh][ts][2], s[qh][ts][3])));
            v = fmaxf(v, __shfl_xor(v, 16));
            v = fmaxf(v, __shfl_xor(v, 32));
            float pm2 = v * L2E;

            if (!__all(pm2 <= m2[qh] + 11.54f)) {   // defer-max, THR = 8 nats
                float mn = fmaxf(m2[qh], pm2);
                float scl = exp2f(m2[qh] - mn);
                lsum[qh] *= scl;
                #pragma unroll
                for (int db = 0; db < 8; ++db)
                    #pragma unroll
                    for (int r = 0; r < 4; ++r) accO[qh][db][r] *= scl;
                m2[qh] = mn;
            }

            #pragma unroll
            for (int ts = 0; ts < 4; ++ts)
                #pragma unroll
                for (int r = 0; r < 4; ++r) {
                    float p = exp2f(fmaf(s[qh][ts][r], L2E, -m2[qh]));
                    lsum[qh] += p;
                    pb[qh][ts & 1][((ts >> 1) << 2) + r] = (half_t)p;
                }
        }

        // ---- PV: K=32, b128 V^T reads shared across both q-halves
        #pragma unroll
        for (int db = 0; db < 8; ++db) {
            int d = db * 16 + li;
            const ushort_t* vbase = &sVc[d * KVB];
            int sw = (d & 7) << 3;
            #pragma unroll
            for (int ks = 0; ks < 2; ++ks) {
                h8 va = *(const h8*)&vbase[(ks * 32 + lg * 8) ^ sw];
                accO[0][db] = mfma16h(va, pb[0][ks], accO[0][db]);
                accO[1][db] = mfma16h(va, pb[1][ks], accO[1][db]);
            }
        }
    }

    // ---- epilogue: finish denominators, normalize, write f32 [B][N][S][D]
    #pragma unroll
    for (int qh = 0; qh < 2; ++qh) {
        float ls = lsum[qh];
        ls += __shfl_xor(ls, 16);
        ls += __shfl_xor(ls, 32);
        float inv = 1.0f / ls;
        int q = q0 + w * 32 + qh * 16 + li;
        size_t base = (((size_t)b * NH + n) * SS + q) * DD;
        #pragma unroll
        for (int db = 0; db < 8; ++db) {
            f4 o;
            #pragma unroll
            for (int r = 0; r < 4; ++r) o[r] = accO[qh][db][r] * inv;
            *(f4*)&Out[base + db * 16 + lg * 4] = o;
        }
    }
}

// ---------------- workspace layout (bytes) ----------------
#define OFF_HC    ((size_t)0)                          // hidden fp16 [MM][HH]
#define OFF_BC    (OFF_HC + (size_t)MM*HH*2)           // Bcat fp16 [NTOT][HH]
#define OFF_BIAS  (OFF_BC + (size_t)NTOT*HH*2)         // bias f32 [NTOT] = 9216 B
#define OFF_O     (OFF_BIAS + (size_t)16384)
#define OFF_VT    (OFF_O + (size_t)MM*NTOT*2)          // Vt fp16 [128][MM]

extern "C" void kernel_launch(void* const* d_in, const int* in_sizes, int n_in,
                              void* d_out, int out_size, void* d_ws, size_t ws_size,
                              hipStream_t stream) {
    const float* hs = (const float*)d_in[0];
    const float* Wq = (const float*)d_in[1];
    const float* bq = (const float*)d_in[2];
    const float* Wk = (const float*)d_in[3];
    const float* bk = (const float*)d_in[4];
    const float* Wv = (const float*)d_in[5];
    const float* bv = (const float*)d_in[6];
    float* out = (float*)d_out;
    char* ws = (char*)d_ws;

    ushort_t* hc   = (ushort_t*)(ws + OFF_HC);
    ushort_t* bcat = (ushort_t*)(ws + OFF_BC);
    float*    bias = (float*)(ws + OFF_BIAS);
    ushort_t* Obuf = (ushort_t*)(ws + OFF_O);
    ushort_t* vt   = (ushort_t*)(ws + OFF_VT);

    // prep
    k_cvt<<<(MM*HH)/(256*8), 256, 0, stream>>>(hs, hc, MM*HH);
    dim3 gwq(HH/64, DD/64, NH);
    k_tw<<<gwq, 256, 0, stream>>>(Wq, bcat, DD);
    dim3 gwk(HH/64, DD/64, 1);
    k_tw<<<gwk, 256, 0, stream>>>(Wk, bcat + (size_t)COL_K*HH, DD);
    k_tw<<<gwk, 256, 0, stream>>>(Wv, bcat + (size_t)COL_V*HH, DD);
    k_bias<<<(NTOT + 255)/256, 256, 0, stream>>>(bq, bk, bv, bias);

    // merged projection GEMM: 4096 x 2304 x 2048
    k_gemm<<<(MM/128)*(NTOT/128), 256, 0, stream>>>(hc, bcat, bias, Obuf);

    // V transpose
    dim3 gt(MM/64, DD/64);
    k_transpose_v<<<gt, 256, 0, stream>>>(Obuf, vt);

    // attention
    dim3 ga(SS/128, NH, NB);
    k_attn<<<ga, 256, 0, stream>>>(Obuf, vt, out);
}

// Round 7
// 133.758 us; speedup vs baseline: 3.7996x; 1.1555x over previous
//
#include <hip/hip_runtime.h>
#include <hip/hip_bf16.h>

typedef unsigned short ushort_t;
typedef _Float16 half_t;
typedef __attribute__((ext_vector_type(8))) _Float16 h8;     // 8 fp16 (K=32 MFMA A/B frag)
typedef __attribute__((ext_vector_type(8))) short short8;
typedef __attribute__((ext_vector_type(4))) float f32x4;
typedef __attribute__((ext_vector_type(4))) float f4;

#define NB 4
#define SS 1024
#define HH 2048
#define NH 16
#define DD 128
#define MM (NB*SS)          // 4096 rows
#define NTOT 2304           // 2048 Q cols | 128 K | 128 V
#define COL_K 2048
#define COL_V 2176
#define KVB 64
#define L2E 1.44269504089f

__device__ __forceinline__ ushort_t f2h(float x) {
    half_t h = (half_t)x;
    return *(ushort_t*)&h;
}
__device__ __forceinline__ f32x4 mfma16h(h8 a, h8 b, f32x4 c) {
    return __builtin_amdgcn_mfma_f32_16x16x32_f16(a, b, c, 0, 0, 0);
}
__device__ __forceinline__ void load_lds16(const ushort_t* g, ushort_t* l) {
    __builtin_amdgcn_global_load_lds(
        (const __attribute__((address_space(1))) unsigned int*)g,
        (__attribute__((address_space(3))) unsigned int*)l,
        16, 0, 0);
}

// ---------------- f32 -> fp16 convert (hidden states) ----------------
__global__ void k_cvt(const float* __restrict__ src, ushort_t* __restrict__ dst, int n) {
    int i = (blockIdx.x * blockDim.x + threadIdx.x) * 8;
    if (i + 7 < n) {
        f4 a = *(const f4*)(src + i);
        f4 b = *(const f4*)(src + i + 4);
        short8 o;
        #pragma unroll
        for (int j = 0; j < 4; ++j) { o[j] = (short)f2h(a[j]); o[4 + j] = (short)f2h(b[j]); }
        *(short8*)(dst + i) = o;
    }
}

// ---------------- tiled weight transpose+convert: W[n][H][Dd] -> T[n*Dd+d][HH] ----------------
__global__ __launch_bounds__(256) void k_tw(const float* __restrict__ W,
                                            ushort_t* __restrict__ T, int Dd) {
    __shared__ ushort_t t[64][74];
    const int n = blockIdx.z;
    const int h0 = blockIdx.x * 64, d0 = blockIdx.y * 64;
    const int r = threadIdx.x >> 2, cg = (threadIdx.x & 3) * 16;
    const float* src = W + ((size_t)n * HH + h0 + r) * Dd + d0 + cg;
    #pragma unroll
    for (int v = 0; v < 4; ++v) {
        f4 a = *(const f4*)(src + v * 4);
        #pragma unroll
        for (int j = 0; j < 4; ++j) t[r][cg + v * 4 + j] = f2h(a[j]);
    }
    __syncthreads();
    short8 o0, o1;
    #pragma unroll
    for (int j = 0; j < 8; ++j) { o0[j] = (short)t[cg + j][r]; o1[j] = (short)t[cg + 8 + j][r]; }
    ushort_t* dst = T + ((size_t)(n * Dd + d0 + r)) * HH + h0 + cg;
    *(short8*)dst = o0;
    *(short8*)(dst + 8) = o1;
}

// ---------------- bias concat [2304] ----------------
__global__ void k_bias(const float* __restrict__ bq, const float* __restrict__ bk,
                       const float* __restrict__ bv, float* __restrict__ bc) {
    int i = blockIdx.x * 256 + threadIdx.x;
    if (i < NTOT)
        bc[i] = (i < COL_K) ? bq[i] : ((i < COL_V) ? bk[i - COL_K] : bv[i - COL_V]);
}

// ---------------- fp16 GEMM: O[M][NTOT] = A[M][HH] * B[NTOT][HH]^T + bias ----------------
__global__ __launch_bounds__(256) void k_gemm(
    const ushort_t* __restrict__ A, const ushort_t* __restrict__ B,
    const float* __restrict__ bias, ushort_t* __restrict__ O) {

    constexpr int BK = 32;
    __shared__ ushort_t sA[128 * BK], sB[128 * BK];

    const int bid = blockIdx.x;
    const int swz = (bid & 7) * 72 + (bid >> 3);     // 576/8 = 72 per XCD, bijective
    const int m0 = (swz & 31) * 128;
    const int n0 = (swz >> 5) * 128;

    const int tid = threadIdx.x;
    const int w = tid >> 6, l = tid & 63;
    const int wr = w >> 1, wc = w & 1;
    f32x4 acc[4][4] = {};

    for (int kt = 0; kt < HH / BK; ++kt) {
        const int k0 = kt * BK;
        #pragma unroll
        for (int c = 0; c < 2; ++c) {
            int chunk = c * 4 + w;
            int idx = chunk * 512 + l * 8;
            int row = idx >> 5, kc = idx & 31;
            load_lds16(A + (size_t)(m0 + row) * HH + k0 + kc, &sA[chunk * 512]);
            load_lds16(B + (size_t)(n0 + row) * HH + k0 + kc, &sB[chunk * 512]);
        }
        __syncthreads();

        h8 a[4], b[4];
        #pragma unroll
        for (int i = 0; i < 4; ++i) {
            int ra = wr * 64 + i * 16 + (l & 15);
            int rb = wc * 64 + i * 16 + (l & 15);
            a[i] = *(const h8*)&sA[ra * 32 + (l >> 4) * 8];
            b[i] = *(const h8*)&sB[rb * 32 + (l >> 4) * 8];
        }
        #pragma unroll
        for (int i = 0; i < 4; ++i)
            #pragma unroll
            for (int j = 0; j < 4; ++j)
                acc[i][j] = mfma16h(a[i], b[j], acc[i][j]);
        __syncthreads();
    }

    #pragma unroll
    for (int i = 0; i < 4; ++i) {
        int row = m0 + wr * 64 + i * 16 + ((l >> 4) << 2);
        #pragma unroll
        for (int j = 0; j < 4; ++j) {
            int col = n0 + wc * 64 + j * 16 + (l & 15);
            float bv = bias[col];
            #pragma unroll
            for (int r = 0; r < 4; ++r) {
                float cv = acc[i][j][r] + bv;
                O[(size_t)(row + r) * NTOT + col] = f2h(cv);
            }
        }
    }
}

// ---------------- V transpose: O cols [COL_V..COL_V+128) -> Vt[128][MM] ----------------
__global__ __launch_bounds__(256) void k_transpose_v(const ushort_t* __restrict__ O,
                                                     ushort_t* __restrict__ Vt) {
    __shared__ ushort_t t[64][74];
    const int tid = threadIdx.x;
    const int bx = blockIdx.x;       // MM/64
    const int by = blockIdx.y;       // 128/64
    int r = tid >> 2, cg = (tid & 3) * 16;
    const ushort_t* src = &O[(size_t)(bx * 64 + r) * NTOT + COL_V + by * 64 + cg];
    short8 v0 = *(const short8*)src;
    short8 v1 = *(const short8*)(src + 8);
    #pragma unroll
    for (int j = 0; j < 8; ++j) { t[r][cg + j] = (ushort_t)v0[j]; t[r][cg + 8 + j] = (ushort_t)v1[j]; }
    __syncthreads();
    short8 o0, o1;
    #pragma unroll
    for (int j = 0; j < 8; ++j) { o0[j] = (short)t[cg + j][r]; o1[j] = (short)t[cg + 8 + j][r]; }
    ushort_t* dst = &Vt[(size_t)(by * 64 + r) * MM + bx * 64 + cg];
    *(short8*)dst = o0;
    *(short8*)(dst + 8) = o1;
}

// ---------------- flash attention: 8 waves x 16 q-rows, permuted QK^T, K=32 PV ----------
// grid (S/128, N, B), 512 thr. Per-lane q = li; t-slices: reg r of s[ts] holds
// t = (ts&1)*32 + lg*8 + (ts>>1)*4 + r  (A-row permutation below), so p[ts&1==ks]
// concatenated over (ts>>1, r) IS the K=32 PV B-fragment. Zero shuffles.
__global__ __launch_bounds__(512, 4) void k_attn(
    const ushort_t* __restrict__ O, const ushort_t* __restrict__ Vt,
    float* __restrict__ Out) {

    __shared__ ushort_t sK[2][KVB * 128];     // [t][128], mask (t&3)|((t>>3)&1)<<2, dbuf
    __shared__ ushort_t sVt[2][128 * KVB];    // [d][KVB], mask d&7, dbuf

    const int tid = threadIdx.x;
    const int w = tid >> 6, l = tid & 63;     // w in [0,8)
    const int lg = l >> 4, li = l & 15;
    const int q0 = blockIdx.x * 128;
    const int n = blockIdx.y, b = blockIdx.z;

    // Q fragments: rows q0 + w*16 + li
    h8 qv[4];
    {
        size_t base = ((size_t)(b * SS + q0 + w * 16 + li)) * NTOT + n * 128 + lg * 8;
        #pragma unroll
        for (int kk = 0; kk < 4; ++kk)
            qv[kk] = *(const h8*)&O[base + kk * 32];
    }

    f32x4 accO[8] = {};
    float m2 = -3.0e38f;
    float lsum = 0.f;

    auto stage = [&](int bi, int t0) {
        #pragma unroll
        for (int c = 0; c < 2; ++c) {
            int seg = c * 8 + w;                         // 16 segs over 8 waves
            int oe = seg * 512 + l * 8;
            int row = oe >> 7;
            int mk = (row & 3) | (((row >> 3) & 1) << 2);
            int ce = (oe & 127) ^ (mk << 3);
            size_t g = (size_t)(b * SS + t0 + row) * NTOT + COL_K + ce;
            load_lds16(O + g, &sK[bi][seg * 512]);
        }
        #pragma unroll
        for (int c = 0; c < 2; ++c) {
            int seg = c * 8 + w;
            int oe = seg * 512 + l * 8;
            int row = oe >> 6;
            int ce = (oe & 63) ^ ((row & 7) << 3);
            size_t g = (size_t)row * MM + b * SS + t0 + ce;
            load_lds16(Vt + g, &sVt[bi][seg * 512]);
        }
    };

    stage(0, 0);
    constexpr int NT = SS / KVB;   // 16

    for (int it = 0; it < NT; ++it) {
        const int cur = it & 1;
        __syncthreads();                       // drains stage(cur)
        if (it + 1 < NT) stage(cur ^ 1, (it + 1) * KVB);
        const ushort_t* sKc = sK[cur];
        const ushort_t* sVc = sVt[cur];

        // ---- QK^T, permuted A-rows
        f32x4 s[4] = {};
        #pragma unroll
        for (int ts = 0; ts < 4; ++ts) {
            int trow = (ts & 1) * 32 + ((li >> 2) << 3) + ((ts >> 1) << 2) + (li & 3);
            int mk = (trow & 3) | (((trow >> 3) & 1) << 2);
            #pragma unroll
            for (int kk = 0; kk < 4; ++kk) {
                h8 kv = *(const h8*)&sKc[trow * 128 + ((kk * 32 + lg * 8) ^ (mk << 3))];
                s[ts] = mfma16h(kv, qv[kk], s[ts]);     // A=K, B=Q -> S^T
            }
        }

        // ---- in-register online softmax (row q = li; 16 t-values per lane)
        float v = fmaxf(fmaxf(s[0][0], s[0][1]), fmaxf(s[0][2], s[0][3]));
        #pragma unroll
        for (int ts = 1; ts < 4; ++ts)
            v = fmaxf(v, fmaxf(fmaxf(s[ts][0], s[ts][1]), fmaxf(s[ts][2], s[ts][3])));
        v = fmaxf(v, __shfl_xor(v, 16));
        v = fmaxf(v, __shfl_xor(v, 32));
        float pm2 = v * L2E;

        if (!__all(pm2 <= m2 + 11.54f)) {   // defer-max, THR = 8 nats
            float mn = fmaxf(m2, pm2);
            float scl = exp2f(m2 - mn);
            lsum *= scl;
            #pragma unroll
            for (int db = 0; db < 8; ++db)
                #pragma unroll
                for (int r = 0; r < 4; ++r) accO[db][r] *= scl;
            m2 = mn;
        }

        h8 pb[2];
        #pragma unroll
        for (int ts = 0; ts < 4; ++ts)
            #pragma unroll
            for (int r = 0; r < 4; ++r) {
                float p = exp2f(fmaf(s[ts][r], L2E, -m2));
                lsum += p;
                pb[ts & 1][((ts >> 1) << 2) + r] = (half_t)p;
            }

        // ---- PV: K=32, b128 V^T reads
        #pragma unroll
        for (int db = 0; db < 8; ++db) {
            int d = db * 16 + li;
            const ushort_t* vbase = &sVc[d * KVB];
            int sw = (d & 7) << 3;
            #pragma unroll
            for (int ks = 0; ks < 2; ++ks) {
                h8 va = *(const h8*)&vbase[(ks * 32 + lg * 8) ^ sw];
                accO[db] = mfma16h(va, pb[ks], accO[db]);
            }
        }
    }

    // ---- epilogue: finish denominator, normalize, write f32 [B][N][S][D]
    lsum += __shfl_xor(lsum, 16);
    lsum += __shfl_xor(lsum, 32);
    float inv = 1.0f / lsum;
    int q = q0 + w * 16 + li;
    size_t base = (((size_t)b * NH + n) * SS + q) * DD;
    #pragma unroll
    for (int db = 0; db < 8; ++db) {
        f4 o;
        #pragma unroll
        for (int r = 0; r < 4; ++r) o[r] = accO[db][r] * inv;
        *(f4*)&Out[base + db * 16 + lg * 4] = o;
    }
}

// ---------------- workspace layout (bytes) ----------------
#define OFF_HC    ((size_t)0)                          // hidden fp16 [MM][HH]
#define OFF_BC    (OFF_HC + (size_t)MM*HH*2)           // Bcat fp16 [NTOT][HH]
#define OFF_BIAS  (OFF_BC + (size_t)NTOT*HH*2)         // bias f32 [NTOT] = 9216 B
#define OFF_O     (OFF_BIAS + (size_t)16384)
#define OFF_VT    (OFF_O + (size_t)MM*NTOT*2)          // Vt fp16 [128][MM]

extern "C" void kernel_launch(void* const* d_in, const int* in_sizes, int n_in,
                              void* d_out, int out_size, void* d_ws, size_t ws_size,
                              hipStream_t stream) {
    const float* hs = (const float*)d_in[0];
    const float* Wq = (const float*)d_in[1];
    const float* bq = (const float*)d_in[2];
    const float* Wk = (const float*)d_in[3];
    const float* bk = (const float*)d_in[4];
    const float* Wv = (const float*)d_in[5];
    const float* bv = (const float*)d_in[6];
    float* out = (float*)d_out;
    char* ws = (char*)d_ws;

    ushort_t* hc   = (ushort_t*)(ws + OFF_HC);
    ushort_t* bcat = (ushort_t*)(ws + OFF_BC);
    float*    bias = (float*)(ws + OFF_BIAS);
    ushort_t* Obuf = (ushort_t*)(ws + OFF_O);
    ushort_t* vt   = (ushort_t*)(ws + OFF_VT);

    // prep
    k_cvt<<<(MM*HH)/(256*8), 256, 0, stream>>>(hs, hc, MM*HH);
    dim3 gwq(HH/64, DD/64, NH);
    k_tw<<<gwq, 256, 0, stream>>>(Wq, bcat, DD);
    dim3 gwk(HH/64, DD/64, 1);
    k_tw<<<gwk, 256, 0, stream>>>(Wk, bcat + (size_t)COL_K*HH, DD);
    k_tw<<<gwk, 256, 0, stream>>>(Wv, bcat + (size_t)COL_V*HH, DD);
    k_bias<<<(NTOT + 255)/256, 256, 0, stream>>>(bq, bk, bv, bias);

    // merged projection GEMM: 4096 x 2304 x 2048
    k_gemm<<<(MM/128)*(NTOT/128), 256, 0, stream>>>(hc, bcat, bias, Obuf);

    // V transpose
    dim3 gt(MM/64, DD/64);
    k_transpose_v<<<gt, 256, 0, stream>>>(Obuf, vt);

    // attention
    dim3 ga(SS/128, NH, NB);
    k_attn<<<ga, 512, 0, stream>>>(Obuf, vt, out);
}